// Round 7
// baseline (428.524 us; speedup 1.0000x reference)
//
#include <hip/hip_runtime.h>

typedef _Float16 half8  __attribute__((ext_vector_type(8)));
typedef _Float16 half4v __attribute__((ext_vector_type(4)));
typedef float    floatx4 __attribute__((ext_vector_type(4)));

#define GLD_LDS16(g, l)                                                        \
  __builtin_amdgcn_global_load_lds(                                            \
      (const __attribute__((address_space(1))) void*)(g),                      \
      (__attribute__((address_space(3))) void*)(l), 16, 0, 0)

// R2-proven forms: clobbered counted waits, builtin barrier, plain ds_reads.
#define SBAR() __builtin_amdgcn_s_barrier()
#define WAITVM3() asm volatile("s_waitcnt vmcnt(3)" ::: "memory")
#define WAITVM0() asm volatile("s_waitcnt vmcnt(0)" ::: "memory")
#define SCHED0() __builtin_amdgcn_sched_barrier(0)

// ---------------------------------------------------------------------------
// C = A * B^T GEMM, A:[M][K] lda, B:[N][K] ldb, f16 in, fp32 acc.
// R7: occupancy-first. 256x128 tile, BK=32, LDS 48 KiB (2 buf x {A 256x32,
// B 128x32}), 512 threads = 8 waves (4M x 2N), per-wave 64x64, acc[4][4]
// (64 acc regs -> combined VGPR+AGPR ~<=128 -> 4 waves/SIMD).
// __launch_bounds__(512,4) => 2 blocks/CU co-resident: block-level TLP hides
// barrier drains and DS bursts (R2..R6 all had 1 block/CU and tied at
// MfmaUtil ~28-29% regardless of schedule engineering).
// Per K-tile: {issue 3 staging loads for k+1 into buf 1-CUR; vmcnt(3) drains
// tile k's 3; barrier; 8 ds_read_b128 + 16 MFMA (compiler-interleaved,
// counted lgkm); barrier}. Never drains vmcnt to 0 mid-loop.
//
// LDS layout per buffer: A chunk (row,kc) at slot row*4 + (kc ^ (row&3)),
// B likewise at +8192 elems. Linear staging dest + pre-swizzled global src.
// ds_read_b128 bank distribution: uniform 8 words/bank (minimum) — free.
// C/D layout (16x16): col = lane&15, row = (lane>>4)*4 + reg  [m89/m91].
//
// XCD swizzle: 1D grid, xcd = bid&7.
//   EPI 0 (QKV): 1536 blocks. j=bid>>3 in [0,192): z=j>>6, mi=(j>>3)&7,
//                n=j&7. m-tile=(xcd*8+mi)*256, n0=(j&7)*128.
//   EPI 2 (scores): 1024 blocks. z=bid&7. j in [0,128): m0=(j>>4)*256,
//                n0=(j&15)*128.
//   EPI 3 (PV): 512 blocks. z=bid&7. j in [0,64): m0=(j>>3)*256,
//                n0=(j&7)*128.
//
// Fused softmax: EPI 2 stores p = exp2((s*scale-4)*log2e) f16 and
// atomicAdds per-row sums of the f16-rounded p; EPI 3 divides by rowsum.
// ---------------------------------------------------------------------------

// stage tile (A: 1024 chunks = 2/thread, B: 512 chunks = 1/thread) into buf c
#define STG(c, ko)                                                             \
  do {                                                                         \
    GLD_LDS16(gA0 + (ko), &lds[(c) * 12288 + tid * 8]);                        \
    GLD_LDS16(gA1 + (ko), &lds[(c) * 12288 + (512 + tid) * 8]);               \
    GLD_LDS16(gB0 + (ko), &lds[(c) * 12288 + 8192 + tid * 8]);                \
  } while (0)

// fragment reads: plain loads (compiler does counted lgkmcnt for MFMA deps;
// R3 proved replacing these with asm + lgkm0 costs ~30%)
#define RDA(dst, c, mt)                                                        \
  do {                                                                         \
    const int ra_ = wm + (mt) * 16 + lr;                                       \
    dst = *(const half8*)&lds[(c) * 12288 +                                    \
                              (ra_ * 4 + (lk ^ (ra_ & 3))) * 8];               \
  } while (0)
#define RDB(dst, c, nt)                                                        \
  do {                                                                         \
    const int rb_ = wn + (nt) * 16 + lr;                                       \
    dst = *(const half8*)&lds[(c) * 12288 + 8192 +                             \
                              (rb_ * 4 + (lk ^ (rb_ & 3))) * 8];               \
  } while (0)

// one K-tile; CUR is a compile-time 0/1 (loop unrolled x2)
#define KBLOCK(CUR, KT)                                                        \
  do {                                                                         \
    const int ko_ = ((KT) + 1) << 5;                                           \
    const bool pf_ = ((KT) + 1 < NT);                                          \
    if (pf_) {                                                                 \
      STG(1 - (CUR), ko_);                                                     \
      WAITVM3();                                                               \
    } else {                                                                   \
      WAITVM0();                                                               \
    }                                                                          \
    SBAR();                                                                    \
    SCHED0();                                                                  \
    half8 af[4], bf[4];                                                        \
    RDA(af[0], CUR, 0); RDA(af[1], CUR, 1);                                    \
    RDA(af[2], CUR, 2); RDA(af[3], CUR, 3);                                    \
    RDB(bf[0], CUR, 0); RDB(bf[1], CUR, 1);                                    \
    RDB(bf[2], CUR, 2); RDB(bf[3], CUR, 3);                                    \
    __builtin_amdgcn_s_setprio(1);                                             \
    _Pragma("unroll") for (int mt_ = 0; mt_ < 4; ++mt_)                        \
        _Pragma("unroll") for (int nt_ = 0; nt_ < 4; ++nt_)                    \
            acc[mt_][nt_] = __builtin_amdgcn_mfma_f32_16x16x32_f16(            \
                af[mt_], bf[nt_], acc[mt_][nt_], 0, 0, 0);                     \
    __builtin_amdgcn_s_setprio(0);                                             \
    SBAR();                                                                    \
  } while (0)

template <int EPI>
__global__ __launch_bounds__(512, 4) void gemm_bt(
    const _Float16* __restrict__ A, const _Float16* __restrict__ B,
    void* __restrict__ Cv, void* __restrict__ Cv2, int lda, int ldb, int ldc,
    int kdim, long long sAz, long long sBz, long long sCz,
    const float* __restrict__ b0, const float* __restrict__ b1,
    const float* __restrict__ b2, float* __restrict__ rowsum, float scale) {
  __shared__ _Float16 lds[24576];  // 48 KiB: [2 buf][A 8192 | B 4096]

  const int bid = blockIdx.x;
  int z, m0, n0;
  if (EPI == 0) {
    const int xcd = bid & 7, j = bid >> 3;  // j in [0,192)
    z = j >> 6;
    m0 = (xcd * 8 + ((j >> 3) & 7)) * 256;
    n0 = (j & 7) * 128;
  } else if (EPI == 2) {
    z = bid & 7;
    const int j = bid >> 3;  // [0,128)
    m0 = (j >> 4) * 256;
    n0 = (j & 15) * 128;
  } else {
    z = bid & 7;
    const int j = bid >> 3;  // [0,64)
    m0 = (j >> 3) * 256;
    n0 = (j & 7) * 128;
  }

  A += (size_t)z * sAz;
  B += (size_t)z * sBz;

  const int tid = threadIdx.x;
  const int wid = tid >> 6;
  const int lane = tid & 63;
  const int wm = (wid >> 1) * 64;  // wave m offset within 256 tile
  const int wn = (wid & 1) * 64;   // wave n offset within 128 tile
  const int lr = lane & 15;
  const int lk = lane >> 4;

  floatx4 acc[4][4];
#pragma unroll
  for (int i = 0; i < 4; ++i)
#pragma unroll
    for (int j = 0; j < 4; ++j)
#pragma unroll
      for (int r = 0; r < 4; ++r) acc[i][j][r] = 0.f;

  // Staging addresses. A: chunk s in [0,1024), s = tid + i*512;
  // B: chunk s = tid in [0,512). row = s>>2, src k-chunk = (s&3)^(row&3).
  {
  }
  const int sa0 = tid, sa1 = tid + 512, sb0 = tid;
  const int ra0 = sa0 >> 2, ca0 = (sa0 & 3) ^ (ra0 & 3);
  const int ra1 = sa1 >> 2, ca1 = (sa1 & 3) ^ (ra1 & 3);
  const int rb0 = sb0 >> 2, cb0 = (sb0 & 3) ^ (rb0 & 3);
  const _Float16* gA0 = A + (size_t)(m0 + ra0) * lda + ca0 * 8;
  const _Float16* gA1 = A + (size_t)(m0 + ra1) * lda + ca1 * 8;
  const _Float16* gB0 = B + (size_t)(n0 + rb0) * ldb + cb0 * 8;

  const int NT = kdim >> 5;  // K-tiles (32 or 64; always even)

  // prologue: stage tile 0 into buf 0, drain, barrier
  STG(0, 0);
  WAITVM0();
  SBAR();

  for (int kt = 0; kt < NT; kt += 2) {
    KBLOCK(0, kt);
    KBLOCK(1, kt + 1);
  }

  if (EPI == 0) {
    const float* bias = (z == 0) ? b0 : ((z == 1) ? b1 : b2);
#pragma unroll
    for (int mt = 0; mt < 4; ++mt) {
#pragma unroll
      for (int nt = 0; nt < 4; ++nt) {
#pragma unroll
        for (int r = 0; r < 4; ++r) {
          const int gm = m0 + wm + mt * 16 + lk * 4 + r;
          const int gn = n0 + wn + nt * 16 + lr;
          const float v = acc[mt][nt][r] + bias[gn];
          if (z < 2) {  // Q / K row-major f16
            ((_Float16*)Cv)[(size_t)z * 16777216 + (size_t)gm * 1024 + gn] =
                (_Float16)v;
          } else {  // V^T[b][d][s] f16
            const int b = gm >> 11, sseq = gm & 2047;
            ((_Float16*)Cv2)[(size_t)b * 2097152 + (size_t)gn * 2048 + sseq] =
                (_Float16)v;
          }
        }
      }
    }
  } else if (EPI == 2) {
    // p = exp2(s*scale*log2e - 4*log2e); store f16, atomic row-sum of
    // f16-rounded p (numerator and denominator use identical values).
    const float c1 = scale * 1.44269504f;
    const float c0e = -5.77078016f;  // -4 * log2(e)
    _Float16* Sout = (_Float16*)Cv + (size_t)z * sCz;
    float* rs = rowsum + z * 2048;
#pragma unroll
    for (int mt = 0; mt < 4; ++mt) {
#pragma unroll
      for (int r = 0; r < 4; ++r) {
        const int gm = m0 + wm + mt * 16 + lk * 4 + r;
        float part = 0.f;
#pragma unroll
        for (int nt = 0; nt < 4; ++nt) {
          const int gn = n0 + wn + nt * 16 + lr;
          const float p = exp2f(fmaf(acc[mt][nt][r], c1, c0e));
          const _Float16 ph = (_Float16)p;
          Sout[(size_t)gm * ldc + gn] = ph;
          part += (float)ph;
        }
#pragma unroll
        for (int o = 1; o < 16; o <<= 1) part += __shfl_xor(part, o);
        if (lr == 0) atomicAdd(&rs[gm], part);
      }
    }
  } else {
    float* O = (float*)Cv + (size_t)z * sCz;
    const float* rs = rowsum + z * 2048;
#pragma unroll
    for (int mt = 0; mt < 4; ++mt) {
#pragma unroll
      for (int r = 0; r < 4; ++r) {
        const int gm = m0 + wm + mt * 16 + lk * 4 + r;
        const float inv = 1.0f / rs[gm];
#pragma unroll
        for (int nt = 0; nt < 4; ++nt) {
          const int gn = n0 + wn + nt * 16 + lr;
          O[(size_t)gm * ldc + gn] = acc[mt][nt][r] * inv;
        }
      }
    }
  }
}

// ---------------------------------------------------------------------------
// Combined prep: blocks [0,16384) convert x fp32->f16 (4 elem/thread);
// blocks [16384,19456) transpose-convert W[h][d] fp32 -> Wt[d][h] f16.
// ---------------------------------------------------------------------------
__global__ __launch_bounds__(256) void prep(
    const float* __restrict__ x, _Float16* __restrict__ xb,
    const float* __restrict__ W0, const float* __restrict__ W1,
    const float* __restrict__ W2, _Float16* __restrict__ Wt) {
  const int bid = blockIdx.x;
  const int tid = threadIdx.x;
  if (bid < 16384) {
    const int i = bid * 256 + tid;
    const float4 v = ((const float4*)x)[i];
    half4v h;
    h[0] = (_Float16)v.x;
    h[1] = (_Float16)v.y;
    h[2] = (_Float16)v.z;
    h[3] = (_Float16)v.w;
    ((half4v*)xb)[i] = h;
    return;
  }
  __shared__ float tile[32][33];
  const int q = bid - 16384;
  const int bz = q >> 10;  // which matrix
  const int t = q & 1023;
  const int d0 = (t & 31) * 32, h0 = (t >> 5) * 32;
  const float* W = bz == 0 ? W0 : (bz == 1 ? W1 : W2);
  _Float16* T = Wt + (size_t)bz * 1048576;
  const int tx = tid & 31, ty = tid >> 5;
#pragma unroll
  for (int i = 0; i < 4; ++i)
    tile[ty + i * 8][tx] = W[(size_t)(h0 + ty + i * 8) * 1024 + d0 + tx];
  __syncthreads();
#pragma unroll
  for (int i = 0; i < 4; ++i)
    T[(size_t)(d0 + ty + i * 8) * 1024 + h0 + tx] =
        (_Float16)tile[tx][ty + i * 8];
}

// ---------------------------------------------------------------------------
// inputs: x[8,2048,1024] f32, Wq[1024,1024], bq[1024], Wk, bk, Wv, bv
// out: [8,2048,1024] f32
// ws layout (bytes): xb f16 @0 (32M), Wt f16 @32M (6M), Q,K f16 @38M (64M),
//   Vt f16 [b][d][s] @102M (32M), S/P f16 @134M (64M) -> ~198M total.
// rowsum fp32 [8][2048] (64 KB) REUSES xb@0: xb is dead after the QKV
// dispatch; the memset is enqueued between QKV and scores (stream-ordered).
// ---------------------------------------------------------------------------
extern "C" void kernel_launch(void* const* d_in, const int* in_sizes, int n_in,
                              void* d_out, int out_size, void* d_ws,
                              size_t ws_size, hipStream_t stream) {
  const float* x = (const float*)d_in[0];
  const float* Wq = (const float*)d_in[1];
  const float* bq = (const float*)d_in[2];
  const float* Wk = (const float*)d_in[3];
  const float* bk = (const float*)d_in[4];
  const float* Wv = (const float*)d_in[5];
  const float* bv = (const float*)d_in[6];
  float* out = (float*)d_out;

  char* w = (char*)d_ws;
  _Float16* xb = (_Float16*)(w);
  _Float16* Wt = (_Float16*)(w + 33554432);
  _Float16* QK = (_Float16*)(w + 39845888);  // Q then K, 16777216 elems each
  _Float16* Vt = (_Float16*)(w + 106954752);
  _Float16* S = (_Float16*)(w + 140509184);
  float* rowsum = (float*)(w);  // overlays dead xb after QKV

  // 1) x -> f16 and W -> Wt[d][h] f16 (one dispatch)
  prep<<<19456, 256, 0, stream>>>(x, xb, Wq, Wk, Wv, Wt);
  // 2) merged QKV projection (XCD-swizzled): M=16384, N=1024, K=1024
  gemm_bt<0><<<1536, 512, 0, stream>>>(xb, Wt, QK, Vt, 1024, 1024, 1024, 1024,
                                       0LL, 1048576LL, 0LL, bq, bk, bv,
                                       nullptr, 1.f);
  // 3) zero rowsum (xb now dead)
  hipMemsetAsync(rowsum, 0, 8 * 2048 * sizeof(float), stream);
  // 4) P = exp((Q K^T)/32 - 4) + row sums; per batch M=N=2048, K=1024
  gemm_bt<2><<<1024, 512, 0, stream>>>(QK, QK + 16777216, S, nullptr, 1024,
                                       1024, 2048, 1024, 2097152LL, 2097152LL,
                                       4194304LL, nullptr, nullptr, nullptr,
                                       rowsum, 0.03125f);
  // 5) out = (P @ Vt^T) / rowsum; per batch M=2048, N=1024, K=2048; fp32 out
  gemm_bt<3><<<512, 512, 0, stream>>>(S, Vt, out, nullptr, 2048, 2048, 1024,
                                      2048, 4194304LL, 2097152LL, 2097152LL,
                                      nullptr, nullptr, nullptr, rowsum, 1.f);

  (void)in_sizes;
  (void)n_in;
  (void)out_size;
  (void)ws_size;
}

// Round 8
// 414.296 us; speedup vs baseline: 1.0343x; 1.0343x over previous
//
#include <hip/hip_runtime.h>

typedef _Float16 half8  __attribute__((ext_vector_type(8)));
typedef _Float16 half4v __attribute__((ext_vector_type(4)));
typedef float    floatx4 __attribute__((ext_vector_type(4)));

#define GLD_LDS16(g, l)                                                        \
  __builtin_amdgcn_global_load_lds(                                            \
      (const __attribute__((address_space(1))) void*)(g),                      \
      (__attribute__((address_space(3))) void*)(l), 16, 0, 0)

// R2-proven forms: clobbered counted waits, builtin barrier, plain ds_reads.
#define SBAR() __builtin_amdgcn_s_barrier()
#define WAITVM3() asm volatile("s_waitcnt vmcnt(3)" ::: "memory")
#define WAITVM0() asm volatile("s_waitcnt vmcnt(0)" ::: "memory")
#define SCHED0() __builtin_amdgcn_sched_barrier(0)

// ---------------------------------------------------------------------------
// C = A * B^T GEMM, A:[M][K] lda, B:[N][K] ldb, f16 in, fp32 acc.
// R8 = R7 + corrected BK=32 swizzle. 256x128 tile, BK=32, LDS 48 KiB
// (2 buf x {A 256x32, B 128x32}), 512 threads = 8 waves (4M x 2N),
// per-wave 64x64, acc[4][4]; __launch_bounds__(512,4) => 2 blocks/CU
// (R7 measured: occupancy 21->37.8%, MfmaUtil 29.4->32.6, QKV 146->140).
//
// SWIZZLE FIX: with 4 chunks/row the row stride is 64B = HALF a bank wrap,
// so f(row)=(row&3) collides rows r and r+4 (same bank base, same XOR) =
// 4-way conflict, measured 12.6M (R7). f(row)=((row>>1)&3) gives each
// 16-lane group all 32 banks at 2 words/bank (b128 minimum, free) and
// 8/bank across the wave. Applied in staging pre-swizzle + both reads.
//
// Per K-tile: {issue 3 staging loads for k+1 into buf 1-CUR; vmcnt(3) drains
// tile k's 3; barrier; 8 ds_read_b128 + 16 MFMA (compiler-interleaved,
// counted lgkm); barrier}. Never drains vmcnt to 0 mid-loop.
// C/D layout (16x16): col = lane&15, row = (lane>>4)*4 + reg  [m89/m91].
//
// XCD swizzle: 1D grid, xcd = bid&7.
//   EPI 0 (QKV): 1536 blocks. j=bid>>3 in [0,192): z=j>>6, mi=(j>>3)&7,
//                n=j&7. m-tile=(xcd*8+mi)*256, n0=(j&7)*128.
//   EPI 2 (scores): 1024 blocks. z=bid&7. j in [0,128): m0=(j>>4)*256,
//                n0=(j&15)*128.
//   EPI 3 (PV): 512 blocks. z=bid&7. j in [0,64): m0=(j>>3)*256,
//                n0=(j&7)*128.
//
// Fused softmax: EPI 2 stores p = exp2((s*scale-4)*log2e) f16 and
// atomicAdds per-row sums of the f16-rounded p; EPI 3 divides by rowsum.
// ---------------------------------------------------------------------------

// stage tile (A: 1024 chunks = 2/thread, B: 512 chunks = 1/thread) into buf c
#define STG(c, ko)                                                             \
  do {                                                                         \
    GLD_LDS16(gA0 + (ko), &lds[(c) * 12288 + tid * 8]);                        \
    GLD_LDS16(gA1 + (ko), &lds[(c) * 12288 + (512 + tid) * 8]);               \
    GLD_LDS16(gB0 + (ko), &lds[(c) * 12288 + 8192 + tid * 8]);                \
  } while (0)

// fragment reads: plain loads (compiler does counted lgkmcnt for MFMA deps;
// R3 proved replacing these with asm + lgkm0 costs ~30%)
#define RDA(dst, c, mt)                                                        \
  do {                                                                         \
    const int ra_ = wm + (mt) * 16 + lr;                                       \
    dst = *(const half8*)&lds[(c) * 12288 +                                    \
                              (ra_ * 4 + (lk ^ ((ra_ >> 1) & 3))) * 8];        \
  } while (0)
#define RDB(dst, c, nt)                                                        \
  do {                                                                         \
    const int rb_ = wn + (nt) * 16 + lr;                                       \
    dst = *(const half8*)&lds[(c) * 12288 + 8192 +                             \
                              (rb_ * 4 + (lk ^ ((rb_ >> 1) & 3))) * 8];        \
  } while (0)

// one K-tile; CUR is a compile-time 0/1 (loop unrolled x2)
#define KBLOCK(CUR, KT)                                                        \
  do {                                                                         \
    const int ko_ = ((KT) + 1) << 5;                                           \
    const bool pf_ = ((KT) + 1 < NT);                                          \
    if (pf_) {                                                                 \
      STG(1 - (CUR), ko_);                                                     \
      WAITVM3();                                                               \
    } else {                                                                   \
      WAITVM0();                                                               \
    }                                                                          \
    SBAR();                                                                    \
    SCHED0();                                                                  \
    half8 af[4], bf[4];                                                        \
    RDA(af[0], CUR, 0); RDA(af[1], CUR, 1);                                    \
    RDA(af[2], CUR, 2); RDA(af[3], CUR, 3);                                    \
    RDB(bf[0], CUR, 0); RDB(bf[1], CUR, 1);                                    \
    RDB(bf[2], CUR, 2); RDB(bf[3], CUR, 3);                                    \
    __builtin_amdgcn_s_setprio(1);                                             \
    _Pragma("unroll") for (int mt_ = 0; mt_ < 4; ++mt_)                        \
        _Pragma("unroll") for (int nt_ = 0; nt_ < 4; ++nt_)                    \
            acc[mt_][nt_] = __builtin_amdgcn_mfma_f32_16x16x32_f16(            \
                af[mt_], bf[nt_], acc[mt_][nt_], 0, 0, 0);                     \
    __builtin_amdgcn_s_setprio(0);                                             \
    SBAR();                                                                    \
  } while (0)

template <int EPI>
__global__ __launch_bounds__(512, 4) void gemm_bt(
    const _Float16* __restrict__ A, const _Float16* __restrict__ B,
    void* __restrict__ Cv, void* __restrict__ Cv2, int lda, int ldb, int ldc,
    int kdim, long long sAz, long long sBz, long long sCz,
    const float* __restrict__ b0, const float* __restrict__ b1,
    const float* __restrict__ b2, float* __restrict__ rowsum, float scale) {
  __shared__ _Float16 lds[24576];  // 48 KiB: [2 buf][A 8192 | B 4096]

  const int bid = blockIdx.x;
  int z, m0, n0;
  if (EPI == 0) {
    const int xcd = bid & 7, j = bid >> 3;  // j in [0,192)
    z = j >> 6;
    m0 = (xcd * 8 + ((j >> 3) & 7)) * 256;
    n0 = (j & 7) * 128;
  } else if (EPI == 2) {
    z = bid & 7;
    const int j = bid >> 3;  // [0,128)
    m0 = (j >> 4) * 256;
    n0 = (j & 15) * 128;
  } else {
    z = bid & 7;
    const int j = bid >> 3;  // [0,64)
    m0 = (j >> 3) * 256;
    n0 = (j & 7) * 128;
  }

  A += (size_t)z * sAz;
  B += (size_t)z * sBz;

  const int tid = threadIdx.x;
  const int wid = tid >> 6;
  const int lane = tid & 63;
  const int wm = (wid >> 1) * 64;  // wave m offset within 256 tile
  const int wn = (wid & 1) * 64;   // wave n offset within 128 tile
  const int lr = lane & 15;
  const int lk = lane >> 4;

  floatx4 acc[4][4];
#pragma unroll
  for (int i = 0; i < 4; ++i)
#pragma unroll
    for (int j = 0; j < 4; ++j)
#pragma unroll
      for (int r = 0; r < 4; ++r) acc[i][j][r] = 0.f;

  // Staging addresses. A: chunk s in [0,1024), s = tid + i*512;
  // B: chunk s = tid in [0,512). row = s>>2; src k-chunk = (s&3)^((row>>1)&3)
  // (involution matching the read swizzle).
  const int sa0 = tid, sa1 = tid + 512, sb0 = tid;
  const int ra0 = sa0 >> 2, ca0 = (sa0 & 3) ^ ((ra0 >> 1) & 3);
  const int ra1 = sa1 >> 2, ca1 = (sa1 & 3) ^ ((ra1 >> 1) & 3);
  const int rb0 = sb0 >> 2, cb0 = (sb0 & 3) ^ ((rb0 >> 1) & 3);
  const _Float16* gA0 = A + (size_t)(m0 + ra0) * lda + ca0 * 8;
  const _Float16* gA1 = A + (size_t)(m0 + ra1) * lda + ca1 * 8;
  const _Float16* gB0 = B + (size_t)(n0 + rb0) * ldb + cb0 * 8;

  const int NT = kdim >> 5;  // K-tiles (32 or 64; always even)

  // prologue: stage tile 0 into buf 0, drain, barrier
  STG(0, 0);
  WAITVM0();
  SBAR();

  for (int kt = 0; kt < NT; kt += 2) {
    KBLOCK(0, kt);
    KBLOCK(1, kt + 1);
  }

  if (EPI == 0) {
    const float* bias = (z == 0) ? b0 : ((z == 1) ? b1 : b2);
#pragma unroll
    for (int mt = 0; mt < 4; ++mt) {
#pragma unroll
      for (int nt = 0; nt < 4; ++nt) {
#pragma unroll
        for (int r = 0; r < 4; ++r) {
          const int gm = m0 + wm + mt * 16 + lk * 4 + r;
          const int gn = n0 + wn + nt * 16 + lr;
          const float v = acc[mt][nt][r] + bias[gn];
          if (z < 2) {  // Q / K row-major f16
            ((_Float16*)Cv)[(size_t)z * 16777216 + (size_t)gm * 1024 + gn] =
                (_Float16)v;
          } else {  // V^T[b][d][s] f16
            const int b = gm >> 11, sseq = gm & 2047;
            ((_Float16*)Cv2)[(size_t)b * 2097152 + (size_t)gn * 2048 + sseq] =
                (_Float16)v;
          }
        }
      }
    }
  } else if (EPI == 2) {
    // p = exp2(s*scale*log2e - 4*log2e); store f16, atomic row-sum of
    // f16-rounded p (numerator and denominator use identical values).
    const float c1 = scale * 1.44269504f;
    const float c0e = -5.77078016f;  // -4 * log2(e)
    _Float16* Sout = (_Float16*)Cv + (size_t)z * sCz;
    float* rs = rowsum + z * 2048;
#pragma unroll
    for (int mt = 0; mt < 4; ++mt) {
#pragma unroll
      for (int r = 0; r < 4; ++r) {
        const int gm = m0 + wm + mt * 16 + lk * 4 + r;
        float part = 0.f;
#pragma unroll
        for (int nt = 0; nt < 4; ++nt) {
          const int gn = n0 + wn + nt * 16 + lr;
          const float p = exp2f(fmaf(acc[mt][nt][r], c1, c0e));
          const _Float16 ph = (_Float16)p;
          Sout[(size_t)gm * ldc + gn] = ph;
          part += (float)ph;
        }
#pragma unroll
        for (int o = 1; o < 16; o <<= 1) part += __shfl_xor(part, o);
        if (lr == 0) atomicAdd(&rs[gm], part);
      }
    }
  } else {
    float* O = (float*)Cv + (size_t)z * sCz;
    const float* rs = rowsum + z * 2048;
#pragma unroll
    for (int mt = 0; mt < 4; ++mt) {
#pragma unroll
      for (int r = 0; r < 4; ++r) {
        const int gm = m0 + wm + mt * 16 + lk * 4 + r;
        const float inv = 1.0f / rs[gm];
#pragma unroll
        for (int nt = 0; nt < 4; ++nt) {
          const int gn = n0 + wn + nt * 16 + lr;
          O[(size_t)gm * ldc + gn] = acc[mt][nt][r] * inv;
        }
      }
    }
  }
}

// ---------------------------------------------------------------------------
// Combined prep: blocks [0,16384) convert x fp32->f16 (4 elem/thread);
// blocks [16384,19456) transpose-convert W[h][d] fp32 -> Wt[d][h] f16.
// ---------------------------------------------------------------------------
__global__ __launch_bounds__(256) void prep(
    const float* __restrict__ x, _Float16* __restrict__ xb,
    const float* __restrict__ W0, const float* __restrict__ W1,
    const float* __restrict__ W2, _Float16* __restrict__ Wt) {
  const int bid = blockIdx.x;
  const int tid = threadIdx.x;
  if (bid < 16384) {
    const int i = bid * 256 + tid;
    const float4 v = ((const float4*)x)[i];
    half4v h;
    h[0] = (_Float16)v.x;
    h[1] = (_Float16)v.y;
    h[2] = (_Float16)v.z;
    h[3] = (_Float16)v.w;
    ((half4v*)xb)[i] = h;
    return;
  }
  __shared__ float tile[32][33];
  const int q = bid - 16384;
  const int bz = q >> 10;  // which matrix
  const int t = q & 1023;
  const int d0 = (t & 31) * 32, h0 = (t >> 5) * 32;
  const float* W = bz == 0 ? W0 : (bz == 1 ? W1 : W2);
  _Float16* T = Wt + (size_t)bz * 1048576;
  const int tx = tid & 31, ty = tid >> 5;
#pragma unroll
  for (int i = 0; i < 4; ++i)
    tile[ty + i * 8][tx] = W[(size_t)(h0 + ty + i * 8) * 1024 + d0 + tx];
  __syncthreads();
#pragma unroll
  for (int i = 0; i < 4; ++i)
    T[(size_t)(d0 + ty + i * 8) * 1024 + h0 + tx] =
        (_Float16)tile[tx][ty + i * 8];
}

// ---------------------------------------------------------------------------
// inputs: x[8,2048,1024] f32, Wq[1024,1024], bq[1024], Wk, bk, Wv, bv
// out: [8,2048,1024] f32
// ws layout (bytes): xb f16 @0 (32M), Wt f16 @32M (6M), Q,K f16 @38M (64M),
//   Vt f16 [b][d][s] @102M (32M), S/P f16 @134M (64M) -> ~198M total.
// rowsum fp32 [8][2048] (64 KB) REUSES xb@0: xb is dead after the QKV
// dispatch; the memset is enqueued between QKV and scores (stream-ordered).
// ---------------------------------------------------------------------------
extern "C" void kernel_launch(void* const* d_in, const int* in_sizes, int n_in,
                              void* d_out, int out_size, void* d_ws,
                              size_t ws_size, hipStream_t stream) {
  const float* x = (const float*)d_in[0];
  const float* Wq = (const float*)d_in[1];
  const float* bq = (const float*)d_in[2];
  const float* Wk = (const float*)d_in[3];
  const float* bk = (const float*)d_in[4];
  const float* Wv = (const float*)d_in[5];
  const float* bv = (const float*)d_in[6];
  float* out = (float*)d_out;

  char* w = (char*)d_ws;
  _Float16* xb = (_Float16*)(w);
  _Float16* Wt = (_Float16*)(w + 33554432);
  _Float16* QK = (_Float16*)(w + 39845888);  // Q then K, 16777216 elems each
  _Float16* Vt = (_Float16*)(w + 106954752);
  _Float16* S = (_Float16*)(w + 140509184);
  float* rowsum = (float*)(w);  // overlays dead xb after QKV

  // 1) x -> f16 and W -> Wt[d][h] f16 (one dispatch)
  prep<<<19456, 256, 0, stream>>>(x, xb, Wq, Wk, Wv, Wt);
  // 2) merged QKV projection (XCD-swizzled): M=16384, N=1024, K=1024
  gemm_bt<0><<<1536, 512, 0, stream>>>(xb, Wt, QK, Vt, 1024, 1024, 1024, 1024,
                                       0LL, 1048576LL, 0LL, bq, bk, bv,
                                       nullptr, 1.f);
  // 3) zero rowsum (xb now dead)
  hipMemsetAsync(rowsum, 0, 8 * 2048 * sizeof(float), stream);
  // 4) P = exp((Q K^T)/32 - 4) + row sums; per batch M=N=2048, K=1024
  gemm_bt<2><<<1024, 512, 0, stream>>>(QK, QK + 16777216, S, nullptr, 1024,
                                       1024, 2048, 1024, 2097152LL, 2097152LL,
                                       4194304LL, nullptr, nullptr, nullptr,
                                       rowsum, 0.03125f);
  // 5) out = (P @ Vt^T) / rowsum; per batch M=2048, N=1024, K=2048; fp32 out
  gemm_bt<3><<<512, 512, 0, stream>>>(S, Vt, out, nullptr, 2048, 2048, 1024,
                                      2048, 4194304LL, 2097152LL, 2097152LL,
                                      nullptr, nullptr, nullptr, rowsum, 1.f);

  (void)in_sizes;
  (void)n_in;
  (void)out_size;
  (void)ws_size;
}